// Round 7
// baseline (611.638 us; speedup 1.0000x reference)
//
#include <hip/hip_runtime.h>
#include <math.h>

#define NTOK   4096
#define DMODEL 1024
#define NHEADS 16
#define HDIM   64
#define KDIM   1024

typedef __attribute__((ext_vector_type(8))) short          bf16x8;
typedef __attribute__((ext_vector_type(4))) float          f32x4;
typedef __attribute__((ext_vector_type(4))) unsigned short us4;

static __device__ __forceinline__ unsigned short f2bf(float f) {
    unsigned int u = __float_as_uint(f);
    u += 0x7fffu + ((u >> 16) & 1u);      // round-to-nearest-even
    return (unsigned short)(u >> 16);
}

// pack two floats -> two bf16 in one dword (lo = a, hi = b)
static __device__ __forceinline__ unsigned int pk2bf(float a, float b) {
#if __has_builtin(__builtin_amdgcn_cvt_pk_bf16_f32)
    return __builtin_bit_cast(unsigned int,
                              __builtin_amdgcn_cvt_pk_bf16_f32(a, b));
#else
    unsigned int ua = __float_as_uint(a) + 0x8000u;   // round-half-up
    unsigned int ub = __float_as_uint(b) + 0x8000u;
    return __builtin_amdgcn_perm(ub, ua, 0x07060302u);
#endif
}

#if __has_builtin(__builtin_amdgcn_exp2f)
#define EXP2(x) __builtin_amdgcn_exp2f(x)
#else
#define EXP2(x) exp2f(x)
#endif

// async 16B global -> LDS (wave-uniform LDS base + lane*16)
static __device__ __forceinline__ void async_copy16(void* lds, const void* g) {
    __builtin_amdgcn_global_load_lds(
        (const __attribute__((address_space(1))) unsigned int*)g,
        (__attribute__((address_space(3))) unsigned int*)lds, 16, 0, 0);
}

// ---------------------------------------------------------------------------
// cast + transpose weights: W [k][n] fp32 -> Wt [n][k] bf16. 64x64 LDS tiles.
// ---------------------------------------------------------------------------
__global__ __launch_bounds__(256)
void cast_wt_kernel(const float* __restrict__ Wq, const float* __restrict__ Wk,
                    const float* __restrict__ Wv, const float* __restrict__ Wo,
                    unsigned short* __restrict__ Tq, unsigned short* __restrict__ Tk,
                    unsigned short* __restrict__ Tv, unsigned short* __restrict__ To) {
    __shared__ float Ws[64][65];
    const float* W;
    unsigned short* T;
    switch (blockIdx.z) {
        case 0:  W = Wq; T = Tq; break;
        case 1:  W = Wk; T = Tk; break;
        case 2:  W = Wv; T = Tv; break;
        default: W = Wo; T = To; break;
    }
    const int k0 = blockIdx.x * 64, n0 = blockIdx.y * 64;
    const int t = threadIdx.x;
    #pragma unroll
    for (int i = 0; i < 4; i++) {
        int c  = i * 256 + t;
        int kk = c >> 4;
        int n4 = (c & 15) << 2;
        *(float4*)(&Ws[kk][n4]) =
            *(const float4*)(W + (size_t)(k0 + kk) * DMODEL + n0 + n4);
    }
    __syncthreads();
    #pragma unroll
    for (int i = 0; i < 4; i++) {
        int c  = i * 256 + t;
        int nn = c >> 4;
        int k4 = (c & 15) << 2;
        us4 o = { f2bf(Ws[k4 + 0][nn]), f2bf(Ws[k4 + 1][nn]),
                  f2bf(Ws[k4 + 2][nn]), f2bf(Ws[k4 + 3][nn]) };
        *(us4*)(T + (size_t)(n0 + nn) * KDIM + k0 + k4) = o;
    }
}

// ---------------------------------------------------------------------------
// cast activations fp32 -> bf16, flat row-major. grid (2048, 3).
// ---------------------------------------------------------------------------
__global__ __launch_bounds__(256)
void cast_in_kernel(const float* __restrict__ q, const float* __restrict__ k,
                    const float* __restrict__ v,
                    unsigned short* __restrict__ Qb,
                    unsigned short* __restrict__ Kb,
                    unsigned short* __restrict__ Vb) {
    const float* src;
    unsigned short* dst;
    switch (blockIdx.y) {
        case 0:  src = q; dst = Qb; break;
        case 1:  src = k; dst = Kb; break;
        default: src = v; dst = Vb; break;
    }
    size_t i = ((size_t)blockIdx.x * 256 + threadIdx.x) * 8;
    float4 f0 = *(const float4*)(src + i);
    float4 f1 = *(const float4*)(src + i + 4);
    uint2 o0 = { pk2bf(f0.x, f0.y), pk2bf(f0.z, f0.w) };
    uint2 o1 = { pk2bf(f1.x, f1.y), pk2bf(f1.z, f1.w) };
    *(uint2*)(dst + i)     = o0;
    *(uint2*)(dst + i + 4) = o1;
}

// ---------------------------------------------------------------------------
// QKV GEMM, pre-cast path: C = Ab(bf16)[4096x1024] x Bt(bf16)^T.
// ---------------------------------------------------------------------------
__global__ __launch_bounds__(256, 3)
void qkv_gemm_pre(const unsigned short* __restrict__ Qb,
                  const unsigned short* __restrict__ Kb,
                  const unsigned short* __restrict__ Vb,
                  const unsigned short* __restrict__ Btq,
                  const unsigned short* __restrict__ Btk,
                  const unsigned short* __restrict__ Btv,
                  unsigned short* __restrict__ Oq, unsigned short* __restrict__ Ok,
                  unsigned short* __restrict__ Ov) {
    __shared__ unsigned short As[128 * 64];
    __shared__ unsigned short Bs[128 * 64];

    const unsigned short* A;
    const unsigned short* Bt;
    unsigned short* Out;
    int mode;
    float sc;
    switch (blockIdx.z) {
        case 0:  A = Qb; Bt = Btq; Out = Oq; mode = 1; sc = 0.18033688011112042f; break;
        case 1:  A = Kb; Bt = Btk; Out = Ok; mode = 1; sc = 1.0f; break;
        default: A = Vb; Bt = Btv; Out = Ov; mode = 2; sc = 1.0f; break;
    }

    const int t    = threadIdx.x;
    const int w    = t >> 6;
    const int lane = t & 63;
    const int quad = lane >> 4;
    const int l15  = lane & 15;
    const int wr   = w >> 1, wc = w & 1;
    const int bm   = blockIdx.y * 128, bn = blockIdx.x * 128;

    f32x4 acc[4][4];
    #pragma unroll
    for (int i = 0; i < 4; i++)
        #pragma unroll
        for (int j = 0; j < 4; j++) acc[i][j] = (f32x4)(0.f);

    for (int k0 = 0; k0 < KDIM; k0 += 64) {
        __syncthreads();
        #pragma unroll
        for (int i = 0; i < 4; i++) {
            int cb = (i * 4 + w) * 64;
            int c  = cb + lane;
            int r  = c >> 3;
            int ko = (c & 7) * 8;
            async_copy16((void*)(Bs + cb * 8),
                         (const void*)(Bt + (size_t)(bn + r) * KDIM + k0 + ko));
            async_copy16((void*)(As + cb * 8),
                         (const void*)(A + (size_t)(bm + r) * KDIM + k0 + ko));
        }
        __syncthreads();
        #pragma unroll
        for (int kq = 0; kq < 2; kq++) {
            bf16x8 af[4], bf[4];
            #pragma unroll
            for (int mt = 0; mt < 4; mt++)
                af[mt] = *(bf16x8*)(As + (wr * 64 + mt * 16 + l15) * 64 + kq * 32 + quad * 8);
            #pragma unroll
            for (int nt = 0; nt < 4; nt++)
                bf[nt] = *(bf16x8*)(Bs + (wc * 64 + nt * 16 + l15) * 64 + kq * 32 + quad * 8);
            #pragma unroll
            for (int mt = 0; mt < 4; mt++)
                #pragma unroll
                for (int nt = 0; nt < 4; nt++)
                    acc[mt][nt] = __builtin_amdgcn_mfma_f32_16x16x32_bf16(
                        af[mt], bf[nt], acc[mt][nt], 0, 0, 0);
        }
    }

    #pragma unroll
    for (int mt = 0; mt < 4; mt++) {
        #pragma unroll
        for (int nt = 0; nt < 4; nt++) {
            int col  = bn + wc * 64 + nt * 16 + l15;
            int row0 = bm + wr * 64 + mt * 16 + quad * 4;
            if (mode == 1) {
                size_t base = ((size_t)(col >> 6)) * NTOK * HDIM + (col & 63);
                #pragma unroll
                for (int r = 0; r < 4; r++)
                    Out[base + (size_t)(row0 + r) * HDIM] = f2bf(acc[mt][nt][r] * sc);
            } else {
                size_t base = ((size_t)(col >> 6)) * HDIM * NTOK +
                              (size_t)(col & 63) * NTOK + row0;
                us4 o = { f2bf(acc[mt][nt][0]), f2bf(acc[mt][nt][1]),
                          f2bf(acc[mt][nt][2]), f2bf(acc[mt][nt][3]) };
                *(us4*)(Out + base) = o;
            }
        }
    }
}

// ---------------------------------------------------------------------------
// QKV GEMM, fallback path (small ws): A fp32 cast in-register.
// ---------------------------------------------------------------------------
__global__ __launch_bounds__(256, 3)
void qkv_gemm(const float* __restrict__ Aq, const float* __restrict__ Ak,
              const float* __restrict__ Av,
              const unsigned short* __restrict__ Btq,
              const unsigned short* __restrict__ Btk,
              const unsigned short* __restrict__ Btv,
              unsigned short* __restrict__ Oq, unsigned short* __restrict__ Ok,
              unsigned short* __restrict__ Ov) {
    __shared__ unsigned short As[128 * 64];
    __shared__ unsigned short Bs[128 * 64];

    const float* A;
    const unsigned short* Bt;
    unsigned short* Out;
    int mode;
    float sc;
    switch (blockIdx.z) {
        case 0:  A = Aq; Bt = Btq; Out = Oq; mode = 1; sc = 0.18033688011112042f; break;
        case 1:  A = Ak; Bt = Btk; Out = Ok; mode = 1; sc = 1.0f; break;
        default: A = Av; Bt = Btv; Out = Ov; mode = 2; sc = 1.0f; break;
    }

    const int t    = threadIdx.x;
    const int w    = t >> 6;
    const int lane = t & 63;
    const int quad = lane >> 4;
    const int l15  = lane & 15;
    const int wr   = w >> 1, wc = w & 1;
    const int bm   = blockIdx.y * 128, bn = blockIdx.x * 128;

    f32x4 acc[4][4];
    #pragma unroll
    for (int i = 0; i < 4; i++)
        #pragma unroll
        for (int j = 0; j < 4; j++) acc[i][j] = (f32x4)(0.f);

    for (int k0 = 0; k0 < KDIM; k0 += 64) {
        __syncthreads();
        #pragma unroll
        for (int i = 0; i < 4; i++) {
            int cb = (i * 4 + w) * 64;
            int c  = cb + lane;
            int r  = c >> 3;
            int ko = (c & 7) * 8;
            async_copy16((void*)(Bs + cb * 8),
                         (const void*)(Bt + (size_t)(bn + r) * KDIM + k0 + ko));
        }
        #pragma unroll
        for (int i = 0; i < 4; i++) {
            int c2 = i * 256 + t;
            int r  = c2 >> 3;
            int k8 = (c2 & 7) * 8;
            const float* src = A + (size_t)(bm + r) * KDIM + k0 + k8;
            float4 f0 = *(const float4*)(src);
            float4 f1 = *(const float4*)(src + 4);
            uint2 p0 = { pk2bf(f0.x, f0.y), pk2bf(f0.z, f0.w) };
            uint2 p1 = { pk2bf(f1.x, f1.y), pk2bf(f1.z, f1.w) };
            *(uint2*)(As + r * 64 + k8)     = p0;
            *(uint2*)(As + r * 64 + k8 + 4) = p1;
        }
        __syncthreads();
        #pragma unroll
        for (int kq = 0; kq < 2; kq++) {
            bf16x8 af[4], bf[4];
            #pragma unroll
            for (int mt = 0; mt < 4; mt++)
                af[mt] = *(bf16x8*)(As + (wr * 64 + mt * 16 + l15) * 64 + kq * 32 + quad * 8);
            #pragma unroll
            for (int nt = 0; nt < 4; nt++)
                bf[nt] = *(bf16x8*)(Bs + (wc * 64 + nt * 16 + l15) * 64 + kq * 32 + quad * 8);
            #pragma unroll
            for (int mt = 0; mt < 4; mt++)
                #pragma unroll
                for (int nt = 0; nt < 4; nt++)
                    acc[mt][nt] = __builtin_amdgcn_mfma_f32_16x16x32_bf16(
                        af[mt], bf[nt], acc[mt][nt], 0, 0, 0);
        }
    }

    #pragma unroll
    for (int mt = 0; mt < 4; mt++) {
        #pragma unroll
        for (int nt = 0; nt < 4; nt++) {
            int col  = bn + wc * 64 + nt * 16 + l15;
            int row0 = bm + wr * 64 + mt * 16 + quad * 4;
            if (mode == 1) {
                size_t base = ((size_t)(col >> 6)) * NTOK * HDIM + (col & 63);
                #pragma unroll
                for (int r = 0; r < 4; r++)
                    Out[base + (size_t)(row0 + r) * HDIM] = f2bf(acc[mt][nt][r] * sc);
            } else {
                size_t base = ((size_t)(col >> 6)) * HDIM * NTOK +
                              (size_t)(col & 63) * NTOK + row0;
                us4 o = { f2bf(acc[mt][nt][0]), f2bf(acc[mt][nt][1]),
                          f2bf(acc[mt][nt][2]), f2bf(acc[mt][nt][3]) };
                *(us4*)(Out + base) = o;
            }
        }
    }
}

// ---------------------------------------------------------------------------
// Output GEMM: out(fp32)[4096x1024] = ctx(bf16) x WoT(bf16)^T.
// 64x128 tile (grid 8 x 64 = 512 blocks = 2/CU) to overlap barrier drains.
// 4 waves as 2x2: wave covers 32 rows x 64 cols (acc 2x4).
// ---------------------------------------------------------------------------
__global__ __launch_bounds__(256, 3)
void out_gemm(const unsigned short* __restrict__ A,
              const unsigned short* __restrict__ Bt,
              float* __restrict__ Out) {
    __shared__ unsigned short As[64 * 64];
    __shared__ unsigned short Bs[128 * 64];

    const int t    = threadIdx.x;
    const int w    = t >> 6;
    const int lane = t & 63;
    const int quad = lane >> 4;
    const int l15  = lane & 15;
    const int wr   = w >> 1, wc = w & 1;
    const int bm   = blockIdx.y * 64, bn = blockIdx.x * 128;

    f32x4 acc[2][4];
    #pragma unroll
    for (int i = 0; i < 2; i++)
        #pragma unroll
        for (int j = 0; j < 4; j++) acc[i][j] = (f32x4)(0.f);

    for (int k0 = 0; k0 < KDIM; k0 += 64) {
        __syncthreads();
        #pragma unroll
        for (int i = 0; i < 4; i++) {        // B: 1024 chunks
            int cb = (i * 4 + w) * 64;
            int c  = cb + lane;
            int r  = c >> 3;
            int ko = (c & 7) * 8;
            async_copy16((void*)(Bs + cb * 8),
                         (const void*)(Bt + (size_t)(bn + r) * KDIM + k0 + ko));
        }
        #pragma unroll
        for (int i = 0; i < 2; i++) {        // A: 512 chunks
            int cb = (i * 4 + w) * 64;
            int c  = cb + lane;
            int r  = c >> 3;
            int ko = (c & 7) * 8;
            async_copy16((void*)(As + cb * 8),
                         (const void*)(A + (size_t)(bm + r) * KDIM + k0 + ko));
        }
        __syncthreads();
        #pragma unroll
        for (int kq = 0; kq < 2; kq++) {
            bf16x8 af[2], bf[4];
            #pragma unroll
            for (int mt = 0; mt < 2; mt++)
                af[mt] = *(bf16x8*)(As + (wr * 32 + mt * 16 + l15) * 64 + kq * 32 + quad * 8);
            #pragma unroll
            for (int nt = 0; nt < 4; nt++)
                bf[nt] = *(bf16x8*)(Bs + (wc * 64 + nt * 16 + l15) * 64 + kq * 32 + quad * 8);
            #pragma unroll
            for (int mt = 0; mt < 2; mt++)
                #pragma unroll
                for (int nt = 0; nt < 4; nt++)
                    acc[mt][nt] = __builtin_amdgcn_mfma_f32_16x16x32_bf16(
                        af[mt], bf[nt], acc[mt][nt], 0, 0, 0);
        }
    }

    #pragma unroll
    for (int mt = 0; mt < 2; mt++) {
        #pragma unroll
        for (int nt = 0; nt < 4; nt++) {
            int col  = bn + wc * 64 + nt * 16 + l15;
            int row0 = bm + wr * 32 + mt * 16 + quad * 4;
            #pragma unroll
            for (int r = 0; r < 4; r++)
                Out[(size_t)(row0 + r) * DMODEL + col] = acc[mt][nt][r];
        }
    }
}

// ---------------------------------------------------------------------------
// Flash attention v7: BARRIER-FREE. K/V fragments read directly from global
// (L2-resident; a wave's 64 lanes cover 16 rows x 64B sectors = minimal
// traffic). LDS used only for the wave-private P C->A layout round-trip.
// 16 q-rows/wave -> 4096 waves = 4 waves/SIMD (grid 1024 = 4 blocks/CU).
// XCD swizzle: h = bid & 15 pins each head's blocks to one XCD (bid%8==h%8),
// per-XCD K/V working set = 2 heads = 2 MB < 4 MB L2.
// Max-free softmax (scale*log2e folded into Q), l via ones-MFMA.
// ---------------------------------------------------------------------------
__global__ __launch_bounds__(256, 4)
void attn_mfma(const unsigned short* __restrict__ Q,
               const unsigned short* __restrict__ K,
               const unsigned short* __restrict__ Vt,
               unsigned short* __restrict__ ctx) {
    __shared__ __align__(16) unsigned short Ps[4][16][72];

    const int bid  = blockIdx.x;
    const int h    = bid & 15;
    const int qt   = bid >> 4;         // 64 q rows per block
    const int t    = threadIdx.x;
    const int w    = t >> 6;
    const int lane = t & 63;
    const int quad = lane >> 4;
    const int l15  = lane & 15;

    // Q fragments (B operand): lane l15 = q row, k = quad*8+j (+32 for kq=1)
    const unsigned short* Qg =
        Q + ((size_t)h * NTOK + qt * 64 + w * 16 + l15) * HDIM;
    bf16x8 qf0 = *(const bf16x8*)(Qg + quad * 8);
    bf16x8 qf1 = *(const bf16x8*)(Qg + 32 + quad * 8);

    // K fragment pointers (A operand): K[key = kc*16 + l15][d = quad*8 + 32*kq]
    // kp0 serves kc={0,1} via imm offsets {0,2048B}, kp1 serves kc={2,3}.
    const unsigned short* kp0 = K + ((size_t)h * NTOK + l15) * HDIM + quad * 8;
    const unsigned short* kp1 = kp0 + 32 * HDIM;
    // V^T fragment pointers: V^T[d = dt*16 + l15][key = quad*8 + 32*kq]
    const unsigned short* vp0 = Vt + ((size_t)h * HDIM + l15) * NTOK + quad * 8;
    const unsigned short* vp1 = vp0 + (size_t)16 * NTOK;
    const unsigned short* vp2 = vp0 + (size_t)32 * NTOK;
    const unsigned short* vp3 = vp0 + (size_t)48 * NTOK;

    const bf16x8 ones = { 16256, 16256, 16256, 16256,
                          16256, 16256, 16256, 16256 };   // bf16 1.0 x8

    f32x4 O[4];
    f32x4 lacc = (f32x4)(0.f);
    #pragma unroll
    for (int dt = 0; dt < 4; dt++) O[dt] = (f32x4)(0.f);

    for (int kt = 0; kt < NTOK / 64; kt++) {
        // ---- S^T = K Q^T : lane owns q-row l15, keys kc*16 + quad*4 + r ----
        f32x4 s[4];
        {
            bf16x8 kf00 = *(const bf16x8*)(kp0);
            bf16x8 kf01 = *(const bf16x8*)(kp0 + 32);
            bf16x8 kf10 = *(const bf16x8*)(kp0 + 16 * HDIM);
            bf16x8 kf11 = *(const bf16x8*)(kp0 + 16 * HDIM + 32);
            bf16x8 kf20 = *(const bf16x8*)(kp1);
            bf16x8 kf21 = *(const bf16x8*)(kp1 + 32);
            bf16x8 kf30 = *(const bf16x8*)(kp1 + 16 * HDIM);
            bf16x8 kf31 = *(const bf16x8*)(kp1 + 16 * HDIM + 32);
            f32x4 a0 = (f32x4)(0.f), a1 = (f32x4)(0.f),
                  a2 = (f32x4)(0.f), a3 = (f32x4)(0.f);
            a0 = __builtin_amdgcn_mfma_f32_16x16x32_bf16(kf00, qf0, a0, 0, 0, 0);
            a1 = __builtin_amdgcn_mfma_f32_16x16x32_bf16(kf10, qf0, a1, 0, 0, 0);
            a2 = __builtin_amdgcn_mfma_f32_16x16x32_bf16(kf20, qf0, a2, 0, 0, 0);
            a3 = __builtin_amdgcn_mfma_f32_16x16x32_bf16(kf30, qf0, a3, 0, 0, 0);
            a0 = __builtin_amdgcn_mfma_f32_16x16x32_bf16(kf01, qf1, a0, 0, 0, 0);
            a1 = __builtin_amdgcn_mfma_f32_16x16x32_bf16(kf11, qf1, a1, 0, 0, 0);
            a2 = __builtin_amdgcn_mfma_f32_16x16x32_bf16(kf21, qf1, a2, 0, 0, 0);
            a3 = __builtin_amdgcn_mfma_f32_16x16x32_bf16(kf31, qf1, a3, 0, 0, 0);
            s[0] = a0; s[1] = a1; s[2] = a2; s[3] = a3;
        }
        kp0 += 64 * HDIM;
        kp1 += 64 * HDIM;

        // ---- V fragments for this key tile (overlap with softmax VALU) ----
        bf16x8 vf00 = *(const bf16x8*)(vp0);
        bf16x8 vf01 = *(const bf16x8*)(vp0 + 32);
        bf16x8 vf10 = *(const bf16x8*)(vp1);
        bf16x8 vf11 = *(const bf16x8*)(vp1 + 32);
        bf16x8 vf20 = *(const bf16x8*)(vp2);
        bf16x8 vf21 = *(const bf16x8*)(vp2 + 32);
        bf16x8 vf30 = *(const bf16x8*)(vp3);
        bf16x8 vf31 = *(const bf16x8*)(vp3 + 32);
        vp0 += 64; vp1 += 64; vp2 += 64; vp3 += 64;

        // ---- max-free softmax: P = exp2(S) -> wave-private LDS ----
        #pragma unroll
        for (int kc = 0; kc < 4; kc++) {
            float e0 = EXP2(s[kc][0]);
            float e1 = EXP2(s[kc][1]);
            float e2 = EXP2(s[kc][2]);
            float e3 = EXP2(s[kc][3]);
            uint2 p = { pk2bf(e0, e1), pk2bf(e2, e3) };
            *(uint2*)(&Ps[w][l15][kc * 16 + quad * 4]) = p;
        }
        asm volatile("s_waitcnt lgkmcnt(0)" ::: "memory");  // P visible (wave-local)

        bf16x8 pf0 = *(bf16x8*)(&Ps[w][l15][quad * 8]);
        bf16x8 pf1 = *(bf16x8*)(&Ps[w][l15][32 + quad * 8]);

        // ---- O^T += V^T P^T, l += 1^T P^T ----
        lacc  = __builtin_amdgcn_mfma_f32_16x16x32_bf16(ones, pf0, lacc, 0, 0, 0);
        O[0]  = __builtin_amdgcn_mfma_f32_16x16x32_bf16(vf00, pf0, O[0], 0, 0, 0);
        O[1]  = __builtin_amdgcn_mfma_f32_16x16x32_bf16(vf10, pf0, O[1], 0, 0, 0);
        O[2]  = __builtin_amdgcn_mfma_f32_16x16x32_bf16(vf20, pf0, O[2], 0, 0, 0);
        O[3]  = __builtin_amdgcn_mfma_f32_16x16x32_bf16(vf30, pf0, O[3], 0, 0, 0);
        lacc  = __builtin_amdgcn_mfma_f32_16x16x32_bf16(ones, pf1, lacc, 0, 0, 0);
        O[0]  = __builtin_amdgcn_mfma_f32_16x16x32_bf16(vf01, pf1, O[0], 0, 0, 0);
        O[1]  = __builtin_amdgcn_mfma_f32_16x16x32_bf16(vf11, pf1, O[1], 0, 0, 0);
        O[2]  = __builtin_amdgcn_mfma_f32_16x16x32_bf16(vf21, pf1, O[2], 0, 0, 0);
        O[3]  = __builtin_amdgcn_mfma_f32_16x16x32_bf16(vf31, pf1, O[3], 0, 0, 0);
    }

    // ---- epilogue: lane l15 owns q-row; d = dt*16 + quad*4 + r ----
    float inv = 1.f / lacc[0];
    size_t row = (size_t)qt * 64 + w * 16 + l15;
    #pragma unroll
    for (int dt = 0; dt < 4; dt++) {
        uint2 o = { pk2bf(O[dt][0] * inv, O[dt][1] * inv),
                    pk2bf(O[dt][2] * inv, O[dt][3] * inv) };
        *(uint2*)(ctx + row * DMODEL + h * HDIM + dt * 16 + quad * 4) = o;
    }
}

// ---------------------------------------------------------------------------
extern "C" void kernel_launch(void* const* d_in, const int* in_sizes, int n_in,
                              void* d_out, int out_size, void* d_ws, size_t ws_size,
                              hipStream_t stream) {
    const float* q  = (const float*)d_in[0];
    const float* k  = (const float*)d_in[1];
    const float* v  = (const float*)d_in[2];
    const float* Wq = (const float*)d_in[3];
    const float* Wk = (const float*)d_in[4];
    const float* Wv = (const float*)d_in[5];
    const float* Wo = (const float*)d_in[6];
    float* out = (float*)d_out;

    unsigned short* WqT = (unsigned short*)d_ws;
    unsigned short* WkT = WqT + (size_t)DMODEL * KDIM;
    unsigned short* WvT = WkT + (size_t)DMODEL * KDIM;
    unsigned short* WoT = WvT + (size_t)DMODEL * KDIM;
    unsigned short* Qh  = WoT + (size_t)DMODEL * KDIM;
    unsigned short* Kh  = Qh  + (size_t)NTOK * DMODEL;
    unsigned short* Vth = Kh  + (size_t)NTOK * DMODEL;
    unsigned short* ctx = Vth + (size_t)NTOK * DMODEL;
    unsigned short* Qb  = ctx + (size_t)NTOK * DMODEL;
    unsigned short* Kb  = Qb  + (size_t)NTOK * DMODEL;
    unsigned short* Vb  = Kb  + (size_t)NTOK * DMODEL;

    const bool precast = ws_size >= (size_t)67108864;   // 64 MB

    cast_wt_kernel<<<dim3(16, 16, 4), 256, 0, stream>>>(Wq, Wk, Wv, Wo,
                                                        WqT, WkT, WvT, WoT);
    if (precast) {
        cast_in_kernel<<<dim3(2048, 3), 256, 0, stream>>>(q, k, v, Qb, Kb, Vb);
        qkv_gemm_pre<<<dim3(DMODEL / 128, NTOK / 128, 3), 256, 0, stream>>>(
            Qb, Kb, Vb, WqT, WkT, WvT, Qh, Kh, Vth);
    } else {
        qkv_gemm<<<dim3(DMODEL / 128, NTOK / 128, 3), 256, 0, stream>>>(
            q, k, v, WqT, WkT, WvT, Qh, Kh, Vth);
    }
    attn_mfma<<<dim3(NTOK / 64 * NHEADS), 256, 0, stream>>>(Qh, Kh, Vth, ctx);
    out_gemm<<<dim3(DMODEL / 128, NTOK / 64), 256, 0, stream>>>(ctx, WoT, out);
}

// Round 8
// 255.983 us; speedup vs baseline: 2.3894x; 2.3894x over previous
//
#include <hip/hip_runtime.h>
#include <math.h>

#define NTOK   4096
#define DMODEL 1024
#define NHEADS 16
#define HDIM   64
#define KDIM   1024

typedef __attribute__((ext_vector_type(8))) short          bf16x8;
typedef __attribute__((ext_vector_type(4))) float          f32x4;
typedef __attribute__((ext_vector_type(4))) unsigned short us4;

static __device__ __forceinline__ unsigned short f2bf(float f) {
    unsigned int u = __float_as_uint(f);
    u += 0x7fffu + ((u >> 16) & 1u);      // round-to-nearest-even
    return (unsigned short)(u >> 16);
}

// pack two floats -> two bf16 in one dword (lo = a, hi = b)
static __device__ __forceinline__ unsigned int pk2bf(float a, float b) {
#if __has_builtin(__builtin_amdgcn_cvt_pk_bf16_f32)
    return __builtin_bit_cast(unsigned int,
                              __builtin_amdgcn_cvt_pk_bf16_f32(a, b));
#else
    unsigned int ua = __float_as_uint(a) + 0x8000u;   // round-half-up
    unsigned int ub = __float_as_uint(b) + 0x8000u;
    return __builtin_amdgcn_perm(ub, ua, 0x07060302u);
#endif
}

#if __has_builtin(__builtin_amdgcn_exp2f)
#define EXP2(x) __builtin_amdgcn_exp2f(x)
#else
#define EXP2(x) exp2f(x)
#endif

// async 16B global -> LDS (wave-uniform LDS base + lane*16)
static __device__ __forceinline__ void async_copy16(void* lds, const void* g) {
    __builtin_amdgcn_global_load_lds(
        (const __attribute__((address_space(1))) unsigned int*)g,
        (__attribute__((address_space(3))) unsigned int*)lds, 16, 0, 0);
}

// ---------------------------------------------------------------------------
// cast + transpose weights: W [k][n] fp32 -> Wt [n][k] bf16. 64x64 LDS tiles.
// ---------------------------------------------------------------------------
__global__ __launch_bounds__(256)
void cast_wt_kernel(const float* __restrict__ Wq, const float* __restrict__ Wk,
                    const float* __restrict__ Wv, const float* __restrict__ Wo,
                    unsigned short* __restrict__ Tq, unsigned short* __restrict__ Tk,
                    unsigned short* __restrict__ Tv, unsigned short* __restrict__ To) {
    __shared__ float Ws[64][65];
    const float* W;
    unsigned short* T;
    switch (blockIdx.z) {
        case 0:  W = Wq; T = Tq; break;
        case 1:  W = Wk; T = Tk; break;
        case 2:  W = Wv; T = Tv; break;
        default: W = Wo; T = To; break;
    }
    const int k0 = blockIdx.x * 64, n0 = blockIdx.y * 64;
    const int t = threadIdx.x;
    #pragma unroll
    for (int i = 0; i < 4; i++) {
        int c  = i * 256 + t;
        int kk = c >> 4;
        int n4 = (c & 15) << 2;
        *(float4*)(&Ws[kk][n4]) =
            *(const float4*)(W + (size_t)(k0 + kk) * DMODEL + n0 + n4);
    }
    __syncthreads();
    #pragma unroll
    for (int i = 0; i < 4; i++) {
        int c  = i * 256 + t;
        int nn = c >> 4;
        int k4 = (c & 15) << 2;
        us4 o = { f2bf(Ws[k4 + 0][nn]), f2bf(Ws[k4 + 1][nn]),
                  f2bf(Ws[k4 + 2][nn]), f2bf(Ws[k4 + 3][nn]) };
        *(us4*)(T + (size_t)(n0 + nn) * KDIM + k0 + k4) = o;
    }
}

// ---------------------------------------------------------------------------
// cast activations fp32 -> bf16, flat row-major. grid (2048, 3).
// ---------------------------------------------------------------------------
__global__ __launch_bounds__(256)
void cast_in_kernel(const float* __restrict__ q, const float* __restrict__ k,
                    const float* __restrict__ v,
                    unsigned short* __restrict__ Qb,
                    unsigned short* __restrict__ Kb,
                    unsigned short* __restrict__ Vb) {
    const float* src;
    unsigned short* dst;
    switch (blockIdx.y) {
        case 0:  src = q; dst = Qb; break;
        case 1:  src = k; dst = Kb; break;
        default: src = v; dst = Vb; break;
    }
    size_t i = ((size_t)blockIdx.x * 256 + threadIdx.x) * 8;
    float4 f0 = *(const float4*)(src + i);
    float4 f1 = *(const float4*)(src + i + 4);
    uint2 o0 = { pk2bf(f0.x, f0.y), pk2bf(f0.z, f0.w) };
    uint2 o1 = { pk2bf(f1.x, f1.y), pk2bf(f1.z, f1.w) };
    *(uint2*)(dst + i)     = o0;
    *(uint2*)(dst + i + 4) = o1;
}

// ---------------------------------------------------------------------------
// QKV GEMM, pre-cast path: C = Ab(bf16)[4096x1024] x Bt(bf16)^T.
// ---------------------------------------------------------------------------
__global__ __launch_bounds__(256, 3)
void qkv_gemm_pre(const unsigned short* __restrict__ Qb,
                  const unsigned short* __restrict__ Kb,
                  const unsigned short* __restrict__ Vb,
                  const unsigned short* __restrict__ Btq,
                  const unsigned short* __restrict__ Btk,
                  const unsigned short* __restrict__ Btv,
                  unsigned short* __restrict__ Oq, unsigned short* __restrict__ Ok,
                  unsigned short* __restrict__ Ov) {
    __shared__ unsigned short As[128 * 64];
    __shared__ unsigned short Bs[128 * 64];

    const unsigned short* A;
    const unsigned short* Bt;
    unsigned short* Out;
    int mode;
    float sc;
    switch (blockIdx.z) {
        case 0:  A = Qb; Bt = Btq; Out = Oq; mode = 1; sc = 0.18033688011112042f; break;
        case 1:  A = Kb; Bt = Btk; Out = Ok; mode = 1; sc = 1.0f; break;
        default: A = Vb; Bt = Btv; Out = Ov; mode = 2; sc = 1.0f; break;
    }

    const int t    = threadIdx.x;
    const int w    = t >> 6;
    const int lane = t & 63;
    const int quad = lane >> 4;
    const int l15  = lane & 15;
    const int wr   = w >> 1, wc = w & 1;
    const int bm   = blockIdx.y * 128, bn = blockIdx.x * 128;

    f32x4 acc[4][4];
    #pragma unroll
    for (int i = 0; i < 4; i++)
        #pragma unroll
        for (int j = 0; j < 4; j++) acc[i][j] = (f32x4)(0.f);

    for (int k0 = 0; k0 < KDIM; k0 += 64) {
        __syncthreads();
        #pragma unroll
        for (int i = 0; i < 4; i++) {
            int cb = (i * 4 + w) * 64;
            int c  = cb + lane;
            int r  = c >> 3;
            int ko = (c & 7) * 8;
            async_copy16((void*)(Bs + cb * 8),
                         (const void*)(Bt + (size_t)(bn + r) * KDIM + k0 + ko));
            async_copy16((void*)(As + cb * 8),
                         (const void*)(A + (size_t)(bm + r) * KDIM + k0 + ko));
        }
        __syncthreads();
        #pragma unroll
        for (int kq = 0; kq < 2; kq++) {
            bf16x8 af[4], bf[4];
            #pragma unroll
            for (int mt = 0; mt < 4; mt++)
                af[mt] = *(bf16x8*)(As + (wr * 64 + mt * 16 + l15) * 64 + kq * 32 + quad * 8);
            #pragma unroll
            for (int nt = 0; nt < 4; nt++)
                bf[nt] = *(bf16x8*)(Bs + (wc * 64 + nt * 16 + l15) * 64 + kq * 32 + quad * 8);
            #pragma unroll
            for (int mt = 0; mt < 4; mt++)
                #pragma unroll
                for (int nt = 0; nt < 4; nt++)
                    acc[mt][nt] = __builtin_amdgcn_mfma_f32_16x16x32_bf16(
                        af[mt], bf[nt], acc[mt][nt], 0, 0, 0);
        }
    }

    #pragma unroll
    for (int mt = 0; mt < 4; mt++) {
        #pragma unroll
        for (int nt = 0; nt < 4; nt++) {
            int col  = bn + wc * 64 + nt * 16 + l15;
            int row0 = bm + wr * 64 + mt * 16 + quad * 4;
            if (mode == 1) {
                size_t base = ((size_t)(col >> 6)) * NTOK * HDIM + (col & 63);
                #pragma unroll
                for (int r = 0; r < 4; r++)
                    Out[base + (size_t)(row0 + r) * HDIM] = f2bf(acc[mt][nt][r] * sc);
            } else {
                size_t base = ((size_t)(col >> 6)) * HDIM * NTOK +
                              (size_t)(col & 63) * NTOK + row0;
                us4 o = { f2bf(acc[mt][nt][0]), f2bf(acc[mt][nt][1]),
                          f2bf(acc[mt][nt][2]), f2bf(acc[mt][nt][3]) };
                *(us4*)(Out + base) = o;
            }
        }
    }
}

// ---------------------------------------------------------------------------
// QKV GEMM, fallback path (small ws): A fp32 cast in-register.
// ---------------------------------------------------------------------------
__global__ __launch_bounds__(256, 3)
void qkv_gemm(const float* __restrict__ Aq, const float* __restrict__ Ak,
              const float* __restrict__ Av,
              const unsigned short* __restrict__ Btq,
              const unsigned short* __restrict__ Btk,
              const unsigned short* __restrict__ Btv,
              unsigned short* __restrict__ Oq, unsigned short* __restrict__ Ok,
              unsigned short* __restrict__ Ov) {
    __shared__ unsigned short As[128 * 64];
    __shared__ unsigned short Bs[128 * 64];

    const float* A;
    const unsigned short* Bt;
    unsigned short* Out;
    int mode;
    float sc;
    switch (blockIdx.z) {
        case 0:  A = Aq; Bt = Btq; Out = Oq; mode = 1; sc = 0.18033688011112042f; break;
        case 1:  A = Ak; Bt = Btk; Out = Ok; mode = 1; sc = 1.0f; break;
        default: A = Av; Bt = Btv; Out = Ov; mode = 2; sc = 1.0f; break;
    }

    const int t    = threadIdx.x;
    const int w    = t >> 6;
    const int lane = t & 63;
    const int quad = lane >> 4;
    const int l15  = lane & 15;
    const int wr   = w >> 1, wc = w & 1;
    const int bm   = blockIdx.y * 128, bn = blockIdx.x * 128;

    f32x4 acc[4][4];
    #pragma unroll
    for (int i = 0; i < 4; i++)
        #pragma unroll
        for (int j = 0; j < 4; j++) acc[i][j] = (f32x4)(0.f);

    for (int k0 = 0; k0 < KDIM; k0 += 64) {
        __syncthreads();
        #pragma unroll
        for (int i = 0; i < 4; i++) {
            int cb = (i * 4 + w) * 64;
            int c  = cb + lane;
            int r  = c >> 3;
            int ko = (c & 7) * 8;
            async_copy16((void*)(Bs + cb * 8),
                         (const void*)(Bt + (size_t)(bn + r) * KDIM + k0 + ko));
        }
        #pragma unroll
        for (int i = 0; i < 4; i++) {
            int c2 = i * 256 + t;
            int r  = c2 >> 3;
            int k8 = (c2 & 7) * 8;
            const float* src = A + (size_t)(bm + r) * KDIM + k0 + k8;
            float4 f0 = *(const float4*)(src);
            float4 f1 = *(const float4*)(src + 4);
            uint2 p0 = { pk2bf(f0.x, f0.y), pk2bf(f0.z, f0.w) };
            uint2 p1 = { pk2bf(f1.x, f1.y), pk2bf(f1.z, f1.w) };
            *(uint2*)(As + r * 64 + k8)     = p0;
            *(uint2*)(As + r * 64 + k8 + 4) = p1;
        }
        __syncthreads();
        #pragma unroll
        for (int kq = 0; kq < 2; kq++) {
            bf16x8 af[4], bf[4];
            #pragma unroll
            for (int mt = 0; mt < 4; mt++)
                af[mt] = *(bf16x8*)(As + (wr * 64 + mt * 16 + l15) * 64 + kq * 32 + quad * 8);
            #pragma unroll
            for (int nt = 0; nt < 4; nt++)
                bf[nt] = *(bf16x8*)(Bs + (wc * 64 + nt * 16 + l15) * 64 + kq * 32 + quad * 8);
            #pragma unroll
            for (int mt = 0; mt < 4; mt++)
                #pragma unroll
                for (int nt = 0; nt < 4; nt++)
                    acc[mt][nt] = __builtin_amdgcn_mfma_f32_16x16x32_bf16(
                        af[mt], bf[nt], acc[mt][nt], 0, 0, 0);
        }
    }

    #pragma unroll
    for (int mt = 0; mt < 4; mt++) {
        #pragma unroll
        for (int nt = 0; nt < 4; nt++) {
            int col  = bn + wc * 64 + nt * 16 + l15;
            int row0 = bm + wr * 64 + mt * 16 + quad * 4;
            if (mode == 1) {
                size_t base = ((size_t)(col >> 6)) * NTOK * HDIM + (col & 63);
                #pragma unroll
                for (int r = 0; r < 4; r++)
                    Out[base + (size_t)(row0 + r) * HDIM] = f2bf(acc[mt][nt][r] * sc);
            } else {
                size_t base = ((size_t)(col >> 6)) * HDIM * NTOK +
                              (size_t)(col & 63) * NTOK + row0;
                us4 o = { f2bf(acc[mt][nt][0]), f2bf(acc[mt][nt][1]),
                          f2bf(acc[mt][nt][2]), f2bf(acc[mt][nt][3]) };
                *(us4*)(Out + base) = o;
            }
        }
    }
}

// ---------------------------------------------------------------------------
// Output GEMM: out(fp32)[4096x1024] = ctx(bf16) x WoT(bf16)^T. 64x128 tile.
// ---------------------------------------------------------------------------
__global__ __launch_bounds__(256, 3)
void out_gemm(const unsigned short* __restrict__ A,
              const unsigned short* __restrict__ Bt,
              float* __restrict__ Out) {
    __shared__ unsigned short As[64 * 64];
    __shared__ unsigned short Bs[128 * 64];

    const int t    = threadIdx.x;
    const int w    = t >> 6;
    const int lane = t & 63;
    const int quad = lane >> 4;
    const int l15  = lane & 15;
    const int wr   = w >> 1, wc = w & 1;
    const int bm   = blockIdx.y * 64, bn = blockIdx.x * 128;

    f32x4 acc[2][4];
    #pragma unroll
    for (int i = 0; i < 2; i++)
        #pragma unroll
        for (int j = 0; j < 4; j++) acc[i][j] = (f32x4)(0.f);

    for (int k0 = 0; k0 < KDIM; k0 += 64) {
        __syncthreads();
        #pragma unroll
        for (int i = 0; i < 4; i++) {
            int cb = (i * 4 + w) * 64;
            int c  = cb + lane;
            int r  = c >> 3;
            int ko = (c & 7) * 8;
            async_copy16((void*)(Bs + cb * 8),
                         (const void*)(Bt + (size_t)(bn + r) * KDIM + k0 + ko));
        }
        #pragma unroll
        for (int i = 0; i < 2; i++) {
            int cb = (i * 4 + w) * 64;
            int c  = cb + lane;
            int r  = c >> 3;
            int ko = (c & 7) * 8;
            async_copy16((void*)(As + cb * 8),
                         (const void*)(A + (size_t)(bm + r) * KDIM + k0 + ko));
        }
        __syncthreads();
        #pragma unroll
        for (int kq = 0; kq < 2; kq++) {
            bf16x8 af[2], bf[4];
            #pragma unroll
            for (int mt = 0; mt < 2; mt++)
                af[mt] = *(bf16x8*)(As + (wr * 32 + mt * 16 + l15) * 64 + kq * 32 + quad * 8);
            #pragma unroll
            for (int nt = 0; nt < 4; nt++)
                bf[nt] = *(bf16x8*)(Bs + (wc * 64 + nt * 16 + l15) * 64 + kq * 32 + quad * 8);
            #pragma unroll
            for (int mt = 0; mt < 2; mt++)
                #pragma unroll
                for (int nt = 0; nt < 4; nt++)
                    acc[mt][nt] = __builtin_amdgcn_mfma_f32_16x16x32_bf16(
                        af[mt], bf[nt], acc[mt][nt], 0, 0, 0);
        }
    }

    #pragma unroll
    for (int mt = 0; mt < 2; mt++) {
        #pragma unroll
        for (int nt = 0; nt < 4; nt++) {
            int col  = bn + wc * 64 + nt * 16 + l15;
            int row0 = bm + wr * 32 + mt * 16 + quad * 4;
            #pragma unroll
            for (int r = 0; r < 4; r++)
                Out[(size_t)(row0 + r) * DMODEL + col] = acc[mt][nt][r];
        }
    }
}

// ---------------------------------------------------------------------------
// Flash attention SPLIT-K: block = (head, 128 q-rows, key-half of 2048).
// 4 waves x 2 q-tiles (32 rows/wave), 32 key-tiles per block.
// Max-free softmax => partials combine by addition: write unnormalized
// O (bf16) + l (fp32) per half; combine kernel normalizes.
// Single-buffer K/V staging (25.6 KB LDS -> 4 blocks/CU, 16 waves/CU).
// ---------------------------------------------------------------------------
__global__ __launch_bounds__(256, 4)
void attn_split(const unsigned short* __restrict__ Q,
                const unsigned short* __restrict__ K,
                const unsigned short* __restrict__ Vt,
                unsigned short* __restrict__ PO,   // [half][row][h*64+d] bf16
                float* __restrict__ lbuf) {        // [half][h][row] fp32
    __shared__ __align__(16) unsigned short Ks[4096];      // [key][d] XOR-chunked
    __shared__ __align__(16) unsigned short Vs[4096];      // [d][key] XOR-chunked
    __shared__ __align__(16) unsigned short Ps[4][16][72]; // [wave][qrow][key]

    const int qt   = blockIdx.x;       // 128 q rows
    const int h    = blockIdx.y;
    const int half = blockIdx.z;       // keys [half*2048, half*2048+2048)
    const int t    = threadIdx.x;
    const int w    = t >> 6;
    const int lane = t & 63;
    const int quad = lane >> 4;
    const int l15  = lane & 15;

    const unsigned short* Qg =
        Q + ((size_t)h * NTOK + qt * 128 + w * 32 + l15) * HDIM;
    bf16x8 qf[2][2];
    qf[0][0] = *(const bf16x8*)(Qg + quad * 8);
    qf[0][1] = *(const bf16x8*)(Qg + 32 + quad * 8);
    qf[1][0] = *(const bf16x8*)(Qg + 16 * HDIM + quad * 8);
    qf[1][1] = *(const bf16x8*)(Qg + 16 * HDIM + 32 + quad * 8);

    const unsigned short* Kg = K  + ((size_t)h * NTOK + half * 2048) * HDIM;
    const unsigned short* Vg = Vt + (size_t)h * HDIM * NTOK + half * 2048;

    // staging source (hoisted): thread covers chunk rr, XOR-swizzled offset
    const int rr = t >> 3;
    const int oo = ((t & 7) ^ (rr & 7)) * 8;
    const unsigned short* kbase = Kg + (size_t)rr * HDIM + oo;
    const unsigned short* vbase = Vg + (size_t)rr * NTOK + oo;
    unsigned short* ksd = Ks + w * 512;   // wave-uniform LDS dest
    unsigned short* vsd = Vs + w * 512;

    // XOR-swizzled fragment read offsets
    const int xb = l15 & 7;
    const int a0 = l15 * 64 + ((quad    ) ^ xb) * 8;
    const int a1 = l15 * 64 + ((quad + 4) ^ xb) * 8;

    const bf16x8 ones = { 16256, 16256, 16256, 16256,
                          16256, 16256, 16256, 16256 };   // bf16 1.0 x8

    f32x4 O[2][4];
    f32x4 lacc[2];
    #pragma unroll
    for (int tl = 0; tl < 2; tl++) {
        lacc[tl] = (f32x4)(0.f);
        #pragma unroll
        for (int dt = 0; dt < 4; dt++) O[tl][dt] = (f32x4)(0.f);
    }

    for (int kt = 0; kt < 32; kt++) {
        __syncthreads();   // Ks/Vs consumption from previous iter complete
        {
            const unsigned short* kp = kbase + (size_t)kt * 64 * HDIM;
            const unsigned short* vp = vbase + kt * 64;
            async_copy16((void*)(ksd),        (const void*)kp);
            async_copy16((void*)(ksd + 2048), (const void*)(kp + 32 * HDIM));
            async_copy16((void*)(vsd),        (const void*)vp);
            async_copy16((void*)(vsd + 2048), (const void*)(vp + (size_t)32 * NTOK));
        }
        __syncthreads();   // staged data visible (compiler drains vmcnt)

        // ---- S^T = K Q^T ----
        f32x4 s[2][4];
        #pragma unroll
        for (int kc = 0; kc < 4; kc++) {
            bf16x8 kf0 = *(bf16x8*)(Ks + kc * 1024 + a0);
            bf16x8 kf1 = *(bf16x8*)(Ks + kc * 1024 + a1);
            #pragma unroll
            for (int tl = 0; tl < 2; tl++) {
                f32x4 acc = (f32x4)(0.f);
                acc = __builtin_amdgcn_mfma_f32_16x16x32_bf16(kf0, qf[tl][0], acc, 0, 0, 0);
                acc = __builtin_amdgcn_mfma_f32_16x16x32_bf16(kf1, qf[tl][1], acc, 0, 0, 0);
                s[tl][kc] = acc;
            }
        }

        // hoist V fragments (shared by both tl)
        bf16x8 vf[4][2];
        #pragma unroll
        for (int dt = 0; dt < 4; dt++) {
            vf[dt][0] = *(bf16x8*)(Vs + dt * 1024 + a0);
            vf[dt][1] = *(bf16x8*)(Vs + dt * 1024 + a1);
        }

        // ---- per-tl: exp2 -> P -> PV (Ps reused; per-wave DS ops in-order) ----
        #pragma unroll
        for (int tl = 0; tl < 2; tl++) {
            #pragma unroll
            for (int kc = 0; kc < 4; kc++) {
                float e0 = EXP2(s[tl][kc][0]);
                float e1 = EXP2(s[tl][kc][1]);
                float e2 = EXP2(s[tl][kc][2]);
                float e3 = EXP2(s[tl][kc][3]);
                uint2 p = { pk2bf(e0, e1), pk2bf(e2, e3) };
                *(uint2*)(&Ps[w][l15][kc * 16 + quad * 4]) = p;
            }
            asm volatile("s_waitcnt lgkmcnt(0)" ::: "memory");

            bf16x8 pf0 = *(bf16x8*)(&Ps[w][l15][quad * 8]);
            bf16x8 pf1 = *(bf16x8*)(&Ps[w][l15][32 + quad * 8]);
            lacc[tl] = __builtin_amdgcn_mfma_f32_16x16x32_bf16(ones, pf0, lacc[tl], 0, 0, 0);
            lacc[tl] = __builtin_amdgcn_mfma_f32_16x16x32_bf16(ones, pf1, lacc[tl], 0, 0, 0);
            #pragma unroll
            for (int dt = 0; dt < 4; dt++) {
                O[tl][dt] = __builtin_amdgcn_mfma_f32_16x16x32_bf16(vf[dt][0], pf0, O[tl][dt], 0, 0, 0);
                O[tl][dt] = __builtin_amdgcn_mfma_f32_16x16x32_bf16(vf[dt][1], pf1, O[tl][dt], 0, 0, 0);
            }
        }
    }

    // ---- epilogue: unnormalized partial O (bf16) + l (fp32) ----
    unsigned short* POh = PO + (size_t)half * NTOK * DMODEL;
    #pragma unroll
    for (int tl = 0; tl < 2; tl++) {
        size_t row = (size_t)qt * 128 + w * 32 + tl * 16 + l15;
        #pragma unroll
        for (int dt = 0; dt < 4; dt++) {
            uint2 o = { pk2bf(O[tl][dt][0], O[tl][dt][1]),
                        pk2bf(O[tl][dt][2], O[tl][dt][3]) };
            *(uint2*)(POh + row * DMODEL + h * HDIM + dt * 16 + quad * 4) = o;
        }
        if (quad == 0)
            lbuf[((size_t)half * NHEADS + h) * NTOK + row] = lacc[tl][0];
    }
}

// ---------------------------------------------------------------------------
// combine: ctx = (Oa + Ob) / (la + lb), bf16 out. 8 elems/thread.
// ---------------------------------------------------------------------------
__global__ __launch_bounds__(256)
void combine_kernel(const unsigned short* __restrict__ PO,
                    const float* __restrict__ lbuf,
                    unsigned short* __restrict__ ctx) {
    size_t idx = ((size_t)blockIdx.x * 256 + threadIdx.x) * 8;
    int row = (int)(idx >> 10);
    int c   = (int)(idx & 1023);
    int h   = c >> 6;
    uint4 a = *(const uint4*)(PO + idx);
    uint4 b = *(const uint4*)(PO + (size_t)NTOK * DMODEL + idx);
    float la = lbuf[(size_t)h * NTOK + row];
    float lb = lbuf[(size_t)NHEADS * NTOK + (size_t)h * NTOK + row];
    float inv = 1.f / (la + lb);
    auto comb = [&](unsigned int x, unsigned int y) -> unsigned int {
        float x0 = __uint_as_float(x << 16);
        float x1 = __uint_as_float(x & 0xffff0000u);
        float y0 = __uint_as_float(y << 16);
        float y1 = __uint_as_float(y & 0xffff0000u);
        return pk2bf((x0 + y0) * inv, (x1 + y1) * inv);
    };
    uint4 o = { comb(a.x, b.x), comb(a.y, b.y), comb(a.z, b.z), comb(a.w, b.w) };
    *(uint4*)(ctx + idx) = o;
}

// ---------------------------------------------------------------------------
// Fallback single-pass attention (round-6 version, for small ws).
// ---------------------------------------------------------------------------
__global__ __launch_bounds__(256)
void attn_mfma(const unsigned short* __restrict__ Q,
               const unsigned short* __restrict__ K,
               const unsigned short* __restrict__ Vt,
               unsigned short* __restrict__ ctx) {
    __shared__ __align__(16) unsigned short Ks[2 * 4096];
    __shared__ __align__(16) unsigned short Vs[2 * 4096];
    __shared__ __align__(16) unsigned short Ps[4][32][72];

    const int h    = blockIdx.y;
    const int qt   = blockIdx.x;
    const int t    = threadIdx.x;
    const int w    = t >> 6;
    const int lane = t & 63;
    const int quad = lane >> 4;
    const int l15  = lane & 15;

    const unsigned short* Qg =
        Q + ((size_t)h * NTOK + qt * 128 + w * 32 + l15) * HDIM;
    bf16x8 qf[2][2];
    qf[0][0] = *(const bf16x8*)(Qg + quad * 8);
    qf[0][1] = *(const bf16x8*)(Qg + 32 + quad * 8);
    qf[1][0] = *(const bf16x8*)(Qg + 16 * HDIM + quad * 8);
    qf[1][1] = *(const bf16x8*)(Qg + 16 * HDIM + 32 + quad * 8);

    const unsigned short* Kg = K  + (size_t)h * NTOK * HDIM;
    const unsigned short* Vg = Vt + (size_t)h * HDIM * NTOK;

    const int rr = t >> 3;
    const int oo = ((t & 7) ^ (rr & 7)) * 8;
    const unsigned short* kbase = Kg + (size_t)rr * HDIM + oo;
    const unsigned short* vbase = Vg + (size_t)rr * NTOK + oo;
    unsigned short* ksd = Ks + w * 512;
    unsigned short* vsd = Vs + w * 512;

    auto stage = [&](int kt, int b) {
        const unsigned short* kp = kbase + (size_t)kt * 64 * HDIM;
        const unsigned short* vp = vbase + kt * 64;
        async_copy16((void*)(ksd + b * 4096),        (const void*)kp);
        async_copy16((void*)(ksd + b * 4096 + 2048), (const void*)(kp + 32 * HDIM));
        async_copy16((void*)(vsd + b * 4096),        (const void*)vp);
        async_copy16((void*)(vsd + b * 4096 + 2048), (const void*)(vp + (size_t)32 * NTOK));
    };

    const int xb = l15 & 7;
    const int a0 = l15 * 64 + ((quad    ) ^ xb) * 8;
    const int a1 = l15 * 64 + ((quad + 4) ^ xb) * 8;

    const bf16x8 ones = { 16256, 16256, 16256, 16256,
                          16256, 16256, 16256, 16256 };

    f32x4 O[2][4];
    f32x4 lacc[2];
    #pragma unroll
    for (int tl = 0; tl < 2; tl++) {
        lacc[tl] = (f32x4)(0.f);
        #pragma unroll
        for (int dt = 0; dt < 4; dt++) O[tl][dt] = (f32x4)(0.f);
    }

    stage(0, 0);

    for (int kt = 0; kt < NTOK / 64; kt++) {
        const int cur = kt & 1;
        __syncthreads();
        if (kt + 1 < NTOK / 64) stage(kt + 1, cur ^ 1);

        f32x4 s[2][4];
        #pragma unroll
        for (int kc = 0; kc < 4; kc++) {
            bf16x8 kf0 = *(bf16x8*)(Ks + cur * 4096 + kc * 1024 + a0);
            bf16x8 kf1 = *(bf16x8*)(Ks + cur * 4096 + kc * 1024 + a1);
            #pragma unroll
            for (int tl = 0; tl < 2; tl++) {
                f32x4 acc = (f32x4)(0.f);
                acc = __builtin_amdgcn_mfma_f32_16x16x32_bf16(kf0, qf[tl][0], acc, 0, 0, 0);
                acc = __builtin_amdgcn_mfma_f32_16x16x32_bf16(kf1, qf[tl][1], acc, 0, 0, 0);
                s[tl][kc] = acc;
            }
        }

        bf16x8 vf[4][2];
        #pragma unroll
        for (int dt = 0; dt < 4; dt++) {
            vf[dt][0] = *(bf16x8*)(Vs + cur * 4096 + dt * 1024 + a0);
            vf[dt][1] = *(bf16x8*)(Vs + cur * 4096 + dt * 1024 + a1);
        }

        #pragma unroll
        for (int tl = 0; tl < 2; tl++) {
            #pragma unroll
            for (int kc = 0; kc < 4; kc++) {
                float e0 = EXP2(s[tl][kc][0]);
                float e1 = EXP2(s[tl][kc][1]);
                float e2 = EXP2(s[tl][kc][2]);
                float e3 = EXP2(s[tl][kc][3]);
                uint2 p = { pk2bf(e0, e1), pk2bf(e2, e3) };
                *(uint2*)(&Ps[w][tl * 16 + l15][kc * 16 + quad * 4]) = p;
            }
            asm volatile("s_waitcnt lgkmcnt(0)" ::: "memory");

            bf16x8 pf0 = *(bf16x8*)(&Ps[w][tl * 16 + l15][quad * 8]);
            bf16x8 pf1 = *(bf16x8*)(&Ps[w][tl * 16 + l15][32 + quad * 8]);
            lacc[tl] = __builtin_amdgcn_mfma_f32_16x16x32_bf16(ones, pf0, lacc[tl], 0, 0, 0);
            lacc[tl] = __builtin_amdgcn_mfma_f32_16x16x32_bf16(ones, pf1, lacc[tl], 0, 0, 0);
            #pragma unroll
            for (int dt = 0; dt < 4; dt++) {
                O[tl][dt] = __builtin_amdgcn_mfma_f32_16x16x32_bf16(vf[dt][0], pf0, O[tl][dt], 0, 0, 0);
                O[tl][dt] = __builtin_amdgcn_mfma_f32_16x16x32_bf16(vf[dt][1], pf1, O[tl][dt], 0, 0, 0);
            }
        }
    }

    #pragma unroll
    for (int tl = 0; tl < 2; tl++) {
        float inv = 1.f / lacc[tl][0];
        size_t row = (size_t)qt * 128 + w * 32 + tl * 16 + l15;
        #pragma unroll
        for (int dt = 0; dt < 4; dt++) {
            uint2 o = { pk2bf(O[tl][dt][0] * inv, O[tl][dt][1] * inv),
                        pk2bf(O[tl][dt][2] * inv, O[tl][dt][3] * inv) };
            *(uint2*)(ctx + row * DMODEL + h * HDIM + dt * 16 + quad * 4) = o;
        }
    }
}

// ---------------------------------------------------------------------------
extern "C" void kernel_launch(void* const* d_in, const int* in_sizes, int n_in,
                              void* d_out, int out_size, void* d_ws, size_t ws_size,
                              hipStream_t stream) {
    const float* q  = (const float*)d_in[0];
    const float* k  = (const float*)d_in[1];
    const float* v  = (const float*)d_in[2];
    const float* Wq = (const float*)d_in[3];
    const float* Wk = (const float*)d_in[4];
    const float* Wv = (const float*)d_in[5];
    const float* Wo = (const float*)d_in[6];
    float* out = (float*)d_out;

    // ws: weights 8MB | Qh,Kh,Vth 24MB | ctx 8MB | scratch 24MB
    // scratch = Qb/Kb/Vb during projections, then PO(16MB)+lbuf(0.5MB) in attn.
    unsigned short* WqT = (unsigned short*)d_ws;
    unsigned short* WkT = WqT + (size_t)DMODEL * KDIM;
    unsigned short* WvT = WkT + (size_t)DMODEL * KDIM;
    unsigned short* WoT = WvT + (size_t)DMODEL * KDIM;
    unsigned short* Qh  = WoT + (size_t)DMODEL * KDIM;
    unsigned short* Kh  = Qh  + (size_t)NTOK * DMODEL;
    unsigned short* Vth = Kh  + (size_t)NTOK * DMODEL;
    unsigned short* ctx = Vth + (size_t)NTOK * DMODEL;
    unsigned short* Qb  = ctx + (size_t)NTOK * DMODEL;
    unsigned short* Kb  = Qb  + (size_t)NTOK * DMODEL;
    unsigned short* Vb  = Kb  + (size_t)NTOK * DMODEL;
    unsigned short* PO  = Qb;                                // overlay (Qb dead)
    float*          lb  = (float*)(PO + (size_t)2 * NTOK * DMODEL);

    const bool bigws = ws_size >= (size_t)67108864;   // 64 MB

    cast_wt_kernel<<<dim3(16, 16, 4), 256, 0, stream>>>(Wq, Wk, Wv, Wo,
                                                        WqT, WkT, WvT, WoT);
    if (bigws) {
        cast_in_kernel<<<dim3(2048, 3), 256, 0, stream>>>(q, k, v, Qb, Kb, Vb);
        qkv_gemm_pre<<<dim3(DMODEL / 128, NTOK / 128, 3), 256, 0, stream>>>(
            Qb, Kb, Vb, WqT, WkT, WvT, Qh, Kh, Vth);
        attn_split<<<dim3(NTOK / 128, NHEADS, 2), 256, 0, stream>>>(
            Qh, Kh, Vth, PO, lb);
        combine_kernel<<<dim3(NTOK * DMODEL / 8 / 256), 256, 0, stream>>>(
            PO, lb, ctx);
    } else {
        qkv_gemm<<<dim3(DMODEL / 128, NTOK / 128, 3), 256, 0, stream>>>(
            q, k, v, WqT, WkT, WvT, Qh, Kh, Vth);
        attn_mfma<<<dim3(NTOK / 128, NHEADS), 256, 0, stream>>>(Qh, Kh, Vth, ctx);
    }
    out_gemm<<<dim3(DMODEL / 128, NTOK / 64), 256, 0, stream>>>(ctx, WoT, out);
}